// Round 2
// baseline (419.511 us; speedup 1.0000x reference)
//
#include <hip/hip_runtime.h>

#define Bv 8
#define Sv 1024
#define Dv 768
#define Hv 12
#define DKv 64
#define Mv (Bv*Sv)          // 8192
#define NQKV (3*Hv*DKv)     // 2304
#define NQK (2*Hv*DKv)      // 1536

typedef __attribute__((ext_vector_type(8))) short short8;
typedef __attribute__((ext_vector_type(4))) float f32x4;

__device__ __forceinline__ short f2bf(float f) {
    unsigned u = __builtin_bit_cast(unsigned, f);
    u += 0x7fffu + ((u >> 16) & 1u);
    return (short)(u >> 16);
}
__device__ __forceinline__ float bf2f(short h) {
    return __builtin_bit_cast(float, (unsigned)(unsigned short)h << 16);
}

__device__ __forceinline__ f32x4 mfma16(short8 a, short8 b, f32x4 c) {
    return __builtin_amdgcn_mfma_f32_16x16x32_bf16(a, b, c, 0, 0, 0);
}

__device__ __forceinline__ void gload16(const short* g, const short* l) {
    __builtin_amdgcn_global_load_lds(
        (const __attribute__((address_space(1))) unsigned int*)g,
        (__attribute__((address_space(3))) unsigned int*)(short*)l, 16, 0, 0);
}

// ---------------- split x (f32 -> bf16 hi + bf16 lo), 8 elems/thread ----------------
__global__ void split_x_kernel(const float* __restrict__ x, short* __restrict__ xh,
                               short* __restrict__ xl) {
    int t = blockIdx.x * 256 + threadIdx.x;
    const float4* f = (const float4*)x + (size_t)t * 2;
    float4 a = f[0], b = f[1];
    float v[8] = {a.x,a.y,a.z,a.w,b.x,b.y,b.z,b.w};
    short8 oh, ol;
#pragma unroll
    for (int k = 0; k < 8; k++) {
        short hi = f2bf(v[k]);
        oh[k] = hi;
        ol[k] = f2bf(v[k] - bf2f(hi));
    }
    *((short8*)xh + t) = oh;
    *((short8*)xl + t) = ol;
}

// ---------------- pack Wq/Wk/Wv -> WqkvT[n][d] hi/lo, n = p*768 + h*64 + kk ----------------
__global__ void pack_wqkv_kernel(const float* __restrict__ Wq, const float* __restrict__ Wk,
                                 const float* __restrict__ Wv, short* __restrict__ Wh,
                                 short* __restrict__ Wl) {
    int dt = blockIdx.x;  // d-tile (64 rows of source [768][64])
    int h  = blockIdx.y;
    int p  = blockIdx.z;
    const float* S = (p == 0 ? Wq : (p == 1 ? Wk : Wv)) + (size_t)h * Dv * DKv;
    __shared__ float lds[64][65];
    int t = threadIdx.x;
    int d0 = dt * 64;
#pragma unroll
    for (int i = 0; i < 4; i++) {
        int v = t + i * 256;          // 1024 float4 total
        int r = v >> 4, c4 = v & 15;
        float4 f = *(const float4*)&S[(size_t)(d0 + r) * DKv + c4 * 4];
        lds[r][c4*4+0] = f.x; lds[r][c4*4+1] = f.y; lds[r][c4*4+2] = f.z; lds[r][c4*4+3] = f.w;
    }
    __syncthreads();
#pragma unroll
    for (int i = 0; i < 2; i++) {
        int v = t + i * 256;          // 512 short8 total
        int kk = v >> 3, dl0 = (v & 7) * 8;
        short8 oh, ol;
#pragma unroll
        for (int k = 0; k < 8; k++) {
            float f = lds[dl0 + k][kk];
            short hi = f2bf(f);
            oh[k] = hi;
            ol[k] = f2bf(f - bf2f(hi));
        }
        size_t base = (size_t)(p*768 + h*64 + kk) * Dv + d0 + dl0;
        *(short8*)&Wh[base] = oh;
        *(short8*)&Wl[base] = ol;
    }
}

// ---------------- transpose+cast (single bf16): D[c][r] = S[r][c] ----------------
__global__ void transpose_cast_kernel(const float* __restrict__ S, int S_cols,
                                      short* __restrict__ D, int D_ld) {
    int c0 = blockIdx.x * 64, r0 = blockIdx.y * 64;
    __shared__ float lds[64][65];
    int t = threadIdx.x;
#pragma unroll
    for (int i = 0; i < 4; i++) {
        int v = t + i * 256;
        int r = v >> 4, c4 = v & 15;
        float4 f = *(const float4*)&S[(size_t)(r0 + r) * S_cols + c0 + c4 * 4];
        lds[r][c4*4+0] = f.x; lds[r][c4*4+1] = f.y; lds[r][c4*4+2] = f.z; lds[r][c4*4+3] = f.w;
    }
    __syncthreads();
#pragma unroll
    for (int i = 0; i < 2; i++) {
        int v = t + i * 256;
        int oc = v >> 3, rl0 = (v & 7) * 8;
        short8 o;
#pragma unroll
        for (int k = 0; k < 8; k++) o[k] = f2bf(lds[rl0 + k][oc]);
        *(short8*)&D[(size_t)(c0 + oc) * D_ld + r0 + rl0] = o;
    }
}

// ---------------- V transpose: Vt[bh*64+dk][s] = Vhi[s][dk] ----------------
__global__ void vtrans_kernel(const short* __restrict__ QKVh, short* __restrict__ Vt) {
    int sc = blockIdx.x;            // 16 chunks of 64 s
    int bh = blockIdx.y;
    int b = bh / Hv, h = bh % Hv;
    __shared__ __align__(16) short lds[64][72];
    int t = threadIdx.x;
    int s0 = sc * 64;
#pragma unroll
    for (int i = 0; i < 2; i++) {
        int v = t + i * 256;
        int sl = v >> 3, c0 = (v & 7) * 8;
        short8 xv = *(const short8*)&QKVh[(size_t)(b*Sv + s0 + sl) * NQKV + NQK + h*DKv + c0];
        *(short8*)&lds[sl][c0] = xv;
    }
    __syncthreads();
#pragma unroll
    for (int i = 0; i < 2; i++) {
        int v = t + i * 256;
        int dk = v >> 3, tl0 = (v & 7) * 8;
        short8 o;
#pragma unroll
        for (int k = 0; k < 8; k++) o[k] = lds[tl0 + k][dk];
        *(short8*)&Vt[(size_t)(bh*64 + dk) * Sv + s0 + tl0] = o;
    }
}

// ---------------- GEMM1 (split): QKV = (xh+xl) @ (Wh+Wl)^T, 3-term ----------------
// 128x128 tile, BK=32, 256 threads. Writes hi bf16 (all cols) + lo bf16 (cols < 1536).
__global__ __launch_bounds__(256) void gemm1_kernel(const short* __restrict__ xh,
                                                    const short* __restrict__ xl,
                                                    const short* __restrict__ Wh,
                                                    const short* __restrict__ Wl,
                                                    short* __restrict__ QKVh,
                                                    short* __restrict__ QKVl) {
    int m0 = blockIdx.y * 128, n0 = blockIdx.x * 128;
    __shared__ __align__(16) short lAh[128 * 32];
    __shared__ __align__(16) short lAl[128 * 32];
    __shared__ __align__(16) short lBh[128 * 32];
    __shared__ __align__(16) short lBl[128 * 32];
    int tid = threadIdx.x, lane = tid & 63, w = tid >> 6;
    int wr = w >> 1, wc = w & 1;
    int li = lane & 15, g = lane >> 4;
    f32x4 zero = {0.f, 0.f, 0.f, 0.f};
    f32x4 acc[4][4];
#pragma unroll
    for (int i = 0; i < 4; i++)
#pragma unroll
        for (int j = 0; j < 4; j++) acc[i][j] = zero;

    int e0 = w * 512 + lane * 8;
    int r0 = e0 >> 5, c0 = e0 & 31;
    int e1 = e0 + 2048;
    int r1 = e1 >> 5, c1 = e1 & 31;

    for (int k0 = 0; k0 < Dv; k0 += 32) {
        __syncthreads();
        gload16(xh + (size_t)(m0 + r0) * Dv + k0 + c0, &lAh[w * 512]);
        gload16(xh + (size_t)(m0 + r1) * Dv + k0 + c1, &lAh[2048 + w * 512]);
        gload16(xl + (size_t)(m0 + r0) * Dv + k0 + c0, &lAl[w * 512]);
        gload16(xl + (size_t)(m0 + r1) * Dv + k0 + c1, &lAl[2048 + w * 512]);
        gload16(Wh + (size_t)(n0 + r0) * Dv + k0 + c0, &lBh[w * 512]);
        gload16(Wh + (size_t)(n0 + r1) * Dv + k0 + c1, &lBh[2048 + w * 512]);
        gload16(Wl + (size_t)(n0 + r0) * Dv + k0 + c0, &lBl[w * 512]);
        gload16(Wl + (size_t)(n0 + r1) * Dv + k0 + c1, &lBl[2048 + w * 512]);
        __syncthreads();
        short8 ah[4], al[4], bh[4], bl[4];
#pragma unroll
        for (int mi = 0; mi < 4; mi++) {
            ah[mi] = *(const short8*)&lAh[(wr*64 + mi*16 + li) * 32 + g * 8];
            al[mi] = *(const short8*)&lAl[(wr*64 + mi*16 + li) * 32 + g * 8];
        }
#pragma unroll
        for (int ni = 0; ni < 4; ni++) {
            bh[ni] = *(const short8*)&lBh[(wc*64 + ni*16 + li) * 32 + g * 8];
            bl[ni] = *(const short8*)&lBl[(wc*64 + ni*16 + li) * 32 + g * 8];
        }
#pragma unroll
        for (int mi = 0; mi < 4; mi++)
#pragma unroll
            for (int ni = 0; ni < 4; ni++) {
                acc[mi][ni] = mfma16(ah[mi], bh[ni], acc[mi][ni]);
                acc[mi][ni] = mfma16(ah[mi], bl[ni], acc[mi][ni]);
                acc[mi][ni] = mfma16(al[mi], bh[ni], acc[mi][ni]);
            }
    }
    bool isv = (n0 >= NQK);
#pragma unroll
    for (int mi = 0; mi < 4; mi++)
#pragma unroll
        for (int ni = 0; ni < 4; ni++)
#pragma unroll
            for (int j = 0; j < 4; j++) {
                int row = m0 + wr*64 + mi*16 + g*4 + j;
                int col = n0 + wc*64 + ni*16 + li;
                float v = acc[mi][ni][j];
                short hi = f2bf(v);
                QKVh[(size_t)row * NQKV + col] = hi;
                if (!isv) QKVl[(size_t)row * NQK + col] = f2bf(v - bf2f(hi));
            }
}

// ---------------- GEMM2: out(f32) = Zb(bf16) @ W2T(bf16)^T ----------------
__global__ __launch_bounds__(256) void gemm2_kernel(const short* __restrict__ A,
                                                    const short* __restrict__ Bt,
                                                    float* __restrict__ C) {
    int m0 = blockIdx.y * 128, n0 = blockIdx.x * 128;
    __shared__ __align__(16) short lA[128 * 32];
    __shared__ __align__(16) short lB[128 * 32];
    int tid = threadIdx.x, lane = tid & 63, w = tid >> 6;
    int wr = w >> 1, wc = w & 1;
    int li = lane & 15, g = lane >> 4;
    f32x4 zero = {0.f, 0.f, 0.f, 0.f};
    f32x4 acc[4][4];
#pragma unroll
    for (int i = 0; i < 4; i++)
#pragma unroll
        for (int j = 0; j < 4; j++) acc[i][j] = zero;

    int e0 = w * 512 + lane * 8;
    int r0 = e0 >> 5, c0 = e0 & 31;
    int e1 = e0 + 2048;
    int r1 = e1 >> 5, c1 = e1 & 31;

    for (int k0 = 0; k0 < Dv; k0 += 32) {
        __syncthreads();
        gload16(A  + (size_t)(m0 + r0) * Dv + k0 + c0, &lA[w * 512]);
        gload16(A  + (size_t)(m0 + r1) * Dv + k0 + c1, &lA[2048 + w * 512]);
        gload16(Bt + (size_t)(n0 + r0) * Dv + k0 + c0, &lB[w * 512]);
        gload16(Bt + (size_t)(n0 + r1) * Dv + k0 + c1, &lB[2048 + w * 512]);
        __syncthreads();
        short8 a[4], bb[4];
#pragma unroll
        for (int mi = 0; mi < 4; mi++)
            a[mi] = *(const short8*)&lA[(wr*64 + mi*16 + li) * 32 + g * 8];
#pragma unroll
        for (int ni = 0; ni < 4; ni++)
            bb[ni] = *(const short8*)&lB[(wc*64 + ni*16 + li) * 32 + g * 8];
#pragma unroll
        for (int mi = 0; mi < 4; mi++)
#pragma unroll
            for (int ni = 0; ni < 4; ni++)
                acc[mi][ni] = mfma16(a[mi], bb[ni], acc[mi][ni]);
    }
#pragma unroll
    for (int mi = 0; mi < 4; mi++)
#pragma unroll
        for (int ni = 0; ni < 4; ni++)
#pragma unroll
            for (int j = 0; j < 4; j++) {
                int row = m0 + wr*64 + mi*16 + g*4 + j;
                int col = n0 + wc*64 + ni*16 + li;
                C[(size_t)row * Dv + col] = acc[mi][ni][j];
            }
}

// ---------------- flash attention (split-bf16 QK^T) ----------------
// grid (16 q-blocks, 96 bh), 256 threads = 4 independent waves, 16 q-rows each.
__global__ __launch_bounds__(256) void attn_kernel(const short* __restrict__ QKVh,
                                                   const short* __restrict__ QKVl,
                                                   const short* __restrict__ Vt,
                                                   short* __restrict__ Z) {
    int qb = blockIdx.x, bh = blockIdx.y;
    int b = bh / Hv, h = bh % Hv;
    int tid = threadIdx.x, lane = tid & 63, w = tid >> 6;
    int li = lane & 15, g = lane >> 4;
    __shared__ __align__(16) short P[4][1024];
    char* Pw = (char*)&P[w][0];

    int qr0 = qb * 64 + w * 16;
    const short* qhr = QKVh + (size_t)(b*Sv + qr0 + li) * NQKV + h * DKv;
    const short* qlr = QKVl + (size_t)(b*Sv + qr0 + li) * NQK  + h * DKv;
    short8 qh0 = *(const short8*)(qhr + g * 8);
    short8 qh1 = *(const short8*)(qhr + 32 + g * 8);
    short8 ql0 = *(const short8*)(qlr + g * 8);
    short8 ql1 = *(const short8*)(qlr + 32 + g * 8);

    const short* Khb = QKVh + (size_t)(b*Sv) * NQKV + Hv*DKv + h*DKv;
    const short* Klb = QKVl + (size_t)(b*Sv) * NQK  + Hv*DKv + h*DKv;
    const short* Vbase = Vt + (size_t)(bh * 64) * Sv;

    float m[4], l[4];
    f32x4 zero = {0.f, 0.f, 0.f, 0.f};
    f32x4 acc[4];
#pragma unroll
    for (int j = 0; j < 4; j++) { m[j] = -1e30f; l[j] = 0.f; }
#pragma unroll
    for (int ni = 0; ni < 4; ni++) acc[ni] = zero;

    for (int t0 = 0; t0 < Sv; t0 += 64) {
        f32x4 s[4];
#pragma unroll
        for (int tn = 0; tn < 4; tn++) {
            const short* krh = Khb + (size_t)(t0 + tn*16 + li) * NQKV;
            const short* krl = Klb + (size_t)(t0 + tn*16 + li) * NQK;
            short8 kh0 = *(const short8*)(krh + g * 8);
            short8 kh1 = *(const short8*)(krh + 32 + g * 8);
            short8 kl0 = *(const short8*)(krl + g * 8);
            short8 kl1 = *(const short8*)(krl + 32 + g * 8);
            f32x4 z = mfma16(qh0, kh0, zero);
            z = mfma16(qh1, kh1, z);
            z = mfma16(qh0, kl0, z);
            z = mfma16(qh1, kl1, z);
            z = mfma16(ql0, kh0, z);
            z = mfma16(ql1, kh1, z);
            s[tn] = z;
        }
#pragma unroll
        for (int tn = 0; tn < 4; tn++)
#pragma unroll
            for (int j = 0; j < 4; j++) s[tn][j] *= 0.125f;

        float p[4][4], sf[4];
#pragma unroll
        for (int j = 0; j < 4; j++) {
            float rm = fmaxf(fmaxf(s[0][j], s[1][j]), fmaxf(s[2][j], s[3][j]));
            rm = fmaxf(rm, __shfl_xor(rm, 1));
            rm = fmaxf(rm, __shfl_xor(rm, 2));
            rm = fmaxf(rm, __shfl_xor(rm, 4));
            rm = fmaxf(rm, __shfl_xor(rm, 8));
            float mn = fmaxf(m[j], rm);
            float sfj = __expf(m[j] - mn);
            float rs = 0.f;
#pragma unroll
            for (int tn = 0; tn < 4; tn++) { p[tn][j] = __expf(s[tn][j] - mn); rs += p[tn][j]; }
            rs += __shfl_xor(rs, 1);
            rs += __shfl_xor(rs, 2);
            rs += __shfl_xor(rs, 4);
            rs += __shfl_xor(rs, 8);
            l[j] = l[j] * sfj + rs;
            m[j] = mn;
            sf[j] = sfj;
        }
#pragma unroll
        for (int ni = 0; ni < 4; ni++)
#pragma unroll
            for (int j = 0; j < 4; j++) acc[ni][j] *= sf[j];

        // P -> LDS ([16 q][64 t], XOR-swizzled 16B chunks within each 128B row)
#pragma unroll
        for (int tn = 0; tn < 4; tn++)
#pragma unroll
            for (int j = 0; j < 4; j++) {
                int q_l = g * 4 + j, t_l = tn * 16 + li;
                int off = (q_l * 128 + t_l * 2) ^ ((q_l & 7) << 4);
                *(short*)(Pw + off) = f2bf(p[tn][j]);
            }
        // PV
#pragma unroll
        for (int kt = 0; kt < 2; kt++) {
            int roff = (li * 128 + kt * 64 + g * 16) ^ ((li & 7) << 4);
            short8 ap = *(const short8*)(Pw + roff);
#pragma unroll
            for (int ni = 0; ni < 4; ni++) {
                const short* vr = Vbase + (size_t)(ni*16 + li) * Sv + t0 + kt*32 + g*8;
                short8 bv = *(const short8*)vr;
                acc[ni] = mfma16(ap, bv, acc[ni]);
            }
        }
    }
    float inv[4];
#pragma unroll
    for (int j = 0; j < 4; j++) inv[j] = 1.f / l[j];
#pragma unroll
    for (int ni = 0; ni < 4; ni++)
#pragma unroll
        for (int j = 0; j < 4; j++) {
            int row = b*Sv + qr0 + g*4 + j;
            int col = h*DKv + ni*16 + li;
            Z[(size_t)row * Dv + col] = f2bf(acc[ni][j] * inv[j]);
        }
}

extern "C" void kernel_launch(void* const* d_in, const int* in_sizes, int n_in,
                              void* d_out, int out_size, void* d_ws, size_t ws_size,
                              hipStream_t stream) {
    const float* x  = (const float*)d_in[0];
    const float* Wq = (const float*)d_in[1];
    const float* Wk = (const float*)d_in[2];
    const float* Wv = (const float*)d_in[3];
    const float* W  = (const float*)d_in[4];
    float* out = (float*)d_out;   // reference output dtype is float32

    short* xh   = (short*)d_ws;                        // 8192*768
    short* xl   = xh   + (size_t)Mv * Dv;              // 8192*768
    short* Wh   = xl   + (size_t)Mv * Dv;              // 2304*768
    short* Wl   = Wh   + (size_t)NQKV * Dv;            // 2304*768
    short* W2T  = Wl   + (size_t)NQKV * Dv;            // 768*768
    short* QKVh = W2T  + (size_t)Dv * Dv;              // 8192*2304
    short* QKVl = QKVh + (size_t)Mv * NQKV;            // 8192*1536
    short* Vt   = QKVl + (size_t)Mv * NQK;             // 96*64*1024
    short* Zb   = Vt   + (size_t)Bv*Hv*DKv * Sv;       // 8192*768

    split_x_kernel<<<dim3(Mv * Dv / (256 * 8)), 256, 0, stream>>>(x, xh, xl);
    pack_wqkv_kernel<<<dim3(Dv/64, Hv, 3), 256, 0, stream>>>(Wq, Wk, Wv, Wh, Wl);
    transpose_cast_kernel<<<dim3(Dv/64, Dv/64), 256, 0, stream>>>(W, Dv, W2T, Dv);
    gemm1_kernel<<<dim3(NQKV/128, Mv/128), 256, 0, stream>>>(xh, xl, Wh, Wl, QKVh, QKVl);
    vtrans_kernel<<<dim3(Sv/64, Bv*Hv), 256, 0, stream>>>(QKVh, Vt);
    attn_kernel<<<dim3(Sv/64, Bv*Hv), 256, 0, stream>>>(QKVh, QKVl, Vt, Zb);
    gemm2_kernel<<<dim3(Dv/128, Mv/128), 256, 0, stream>>>(Zb, W2T, out);
}

// Round 3
// 374.821 us; speedup vs baseline: 1.1192x; 1.1192x over previous
//
#include <hip/hip_runtime.h>

#define Bv 8
#define Sv 1024
#define Dv 768
#define Hv 12
#define DKv 64
#define Mv (Bv*Sv)          // 8192
#define NQKV (3*Hv*DKv)     // 2304
#define NQK (2*Hv*DKv)      // 1536

typedef __attribute__((ext_vector_type(8))) short short8;
typedef __attribute__((ext_vector_type(4))) float f32x4;

__device__ __forceinline__ short f2bf(float f) {
    unsigned u = __builtin_bit_cast(unsigned, f);
    u += 0x7fffu + ((u >> 16) & 1u);
    return (short)(u >> 16);
}
__device__ __forceinline__ float bf2f(short h) {
    return __builtin_bit_cast(float, (unsigned)(unsigned short)h << 16);
}

__device__ __forceinline__ f32x4 mfma16(short8 a, short8 b, f32x4 c) {
    return __builtin_amdgcn_mfma_f32_16x16x32_bf16(a, b, c, 0, 0, 0);
}

__device__ __forceinline__ void gload16(const short* g, const short* l) {
    __builtin_amdgcn_global_load_lds(
        (const __attribute__((address_space(1))) unsigned int*)g,
        (__attribute__((address_space(3))) unsigned int*)(short*)l, 16, 0, 0);
}

// ---------------- split x (f32 -> bf16 hi + bf16 lo), 8 elems/thread ----------------
__global__ void split_x_kernel(const float* __restrict__ x, short* __restrict__ xh,
                               short* __restrict__ xl) {
    int t = blockIdx.x * 256 + threadIdx.x;
    const float4* f = (const float4*)x + (size_t)t * 2;
    float4 a = f[0], b = f[1];
    float v[8] = {a.x,a.y,a.z,a.w,b.x,b.y,b.z,b.w};
    short8 oh, ol;
#pragma unroll
    for (int k = 0; k < 8; k++) {
        short hi = f2bf(v[k]);
        oh[k] = hi;
        ol[k] = f2bf(v[k] - bf2f(hi));
    }
    *((short8*)xh + t) = oh;
    *((short8*)xl + t) = ol;
}

// ---------------- pack Wq/Wk/Wv -> WqkvT[n][d] hi/lo, n = p*768 + h*64 + kk ----------------
__global__ void pack_wqkv_kernel(const float* __restrict__ Wq, const float* __restrict__ Wk,
                                 const float* __restrict__ Wv, short* __restrict__ Wh,
                                 short* __restrict__ Wl) {
    int dt = blockIdx.x;  // d-tile (64 rows of source [768][64])
    int h  = blockIdx.y;
    int p  = blockIdx.z;
    const float* S = (p == 0 ? Wq : (p == 1 ? Wk : Wv)) + (size_t)h * Dv * DKv;
    __shared__ float lds[64][65];
    int t = threadIdx.x;
    int d0 = dt * 64;
#pragma unroll
    for (int i = 0; i < 4; i++) {
        int v = t + i * 256;          // 1024 float4 total
        int r = v >> 4, c4 = v & 15;
        float4 f = *(const float4*)&S[(size_t)(d0 + r) * DKv + c4 * 4];
        lds[r][c4*4+0] = f.x; lds[r][c4*4+1] = f.y; lds[r][c4*4+2] = f.z; lds[r][c4*4+3] = f.w;
    }
    __syncthreads();
#pragma unroll
    for (int i = 0; i < 2; i++) {
        int v = t + i * 256;          // 512 short8 total
        int kk = v >> 3, dl0 = (v & 7) * 8;
        short8 oh, ol;
#pragma unroll
        for (int k = 0; k < 8; k++) {
            float f = lds[dl0 + k][kk];
            short hi = f2bf(f);
            oh[k] = hi;
            ol[k] = f2bf(f - bf2f(hi));
        }
        size_t base = (size_t)(p*768 + h*64 + kk) * Dv + d0 + dl0;
        *(short8*)&Wh[base] = oh;
        if (p < 2) *(short8*)&Wl[base] = ol;   // V never feeds scores: lo unused
    }
}

// ---------------- transpose+cast (single bf16): D[c][r] = S[r][c] ----------------
__global__ void transpose_cast_kernel(const float* __restrict__ S, int S_cols,
                                      short* __restrict__ D, int D_ld) {
    int c0 = blockIdx.x * 64, r0 = blockIdx.y * 64;
    __shared__ float lds[64][65];
    int t = threadIdx.x;
#pragma unroll
    for (int i = 0; i < 4; i++) {
        int v = t + i * 256;
        int r = v >> 4, c4 = v & 15;
        float4 f = *(const float4*)&S[(size_t)(r0 + r) * S_cols + c0 + c4 * 4];
        lds[r][c4*4+0] = f.x; lds[r][c4*4+1] = f.y; lds[r][c4*4+2] = f.z; lds[r][c4*4+3] = f.w;
    }
    __syncthreads();
#pragma unroll
    for (int i = 0; i < 2; i++) {
        int v = t + i * 256;
        int oc = v >> 3, rl0 = (v & 7) * 8;
        short8 o;
#pragma unroll
        for (int k = 0; k < 8; k++) o[k] = f2bf(lds[rl0 + k][oc]);
        *(short8*)&D[(size_t)(c0 + oc) * D_ld + r0 + rl0] = o;
    }
}

// ---------------- V transpose: Vt[bh*64+dk][s] = Vhi[s][dk] ----------------
__global__ void vtrans_kernel(const short* __restrict__ QKVh, short* __restrict__ Vt) {
    int sc = blockIdx.x;            // 16 chunks of 64 s
    int bh = blockIdx.y;
    int b = bh / Hv, h = bh % Hv;
    __shared__ __align__(16) short lds[64][72];
    int t = threadIdx.x;
    int s0 = sc * 64;
#pragma unroll
    for (int i = 0; i < 2; i++) {
        int v = t + i * 256;
        int sl = v >> 3, c0 = (v & 7) * 8;
        short8 xv = *(const short8*)&QKVh[(size_t)(b*Sv + s0 + sl) * NQKV + NQK + h*DKv + c0];
        *(short8*)&lds[sl][c0] = xv;
    }
    __syncthreads();
#pragma unroll
    for (int i = 0; i < 2; i++) {
        int v = t + i * 256;
        int dk = v >> 3, tl0 = (v & 7) * 8;
        short8 o;
#pragma unroll
        for (int k = 0; k < 8; k++) o[k] = lds[tl0 + k][dk];
        *(short8*)&Vt[(size_t)(bh*64 + dk) * Sv + s0 + tl0] = o;
    }
}

// ---------------- GEMM1 (split): QKV = (xh+xl) @ (Wh+Wl)^T ----------------
// 3-term split for Q/K columns; hi-only for V columns (they never feed scores).
__global__ __launch_bounds__(256) void gemm1_kernel(const short* __restrict__ xh,
                                                    const short* __restrict__ xl,
                                                    const short* __restrict__ Wh,
                                                    const short* __restrict__ Wl,
                                                    short* __restrict__ QKVh,
                                                    short* __restrict__ QKVl) {
    int m0 = blockIdx.y * 128, n0 = blockIdx.x * 128;
    bool isv = (n0 >= NQK);
    __shared__ __align__(16) short lAh[128 * 32];
    __shared__ __align__(16) short lAl[128 * 32];
    __shared__ __align__(16) short lBh[128 * 32];
    __shared__ __align__(16) short lBl[128 * 32];
    int tid = threadIdx.x, lane = tid & 63, w = tid >> 6;
    int wr = w >> 1, wc = w & 1;
    int li = lane & 15, g = lane >> 4;
    f32x4 zero = {0.f, 0.f, 0.f, 0.f};
    f32x4 acc[4][4];
#pragma unroll
    for (int i = 0; i < 4; i++)
#pragma unroll
        for (int j = 0; j < 4; j++) acc[i][j] = zero;

    int e0 = w * 512 + lane * 8;
    int r0 = e0 >> 5, c0 = e0 & 31;
    int e1 = e0 + 2048;
    int r1 = e1 >> 5, c1 = e1 & 31;

    for (int k0 = 0; k0 < Dv; k0 += 32) {
        __syncthreads();
        gload16(xh + (size_t)(m0 + r0) * Dv + k0 + c0, &lAh[w * 512]);
        gload16(xh + (size_t)(m0 + r1) * Dv + k0 + c1, &lAh[2048 + w * 512]);
        gload16(Wh + (size_t)(n0 + r0) * Dv + k0 + c0, &lBh[w * 512]);
        gload16(Wh + (size_t)(n0 + r1) * Dv + k0 + c1, &lBh[2048 + w * 512]);
        if (!isv) {
            gload16(xl + (size_t)(m0 + r0) * Dv + k0 + c0, &lAl[w * 512]);
            gload16(xl + (size_t)(m0 + r1) * Dv + k0 + c1, &lAl[2048 + w * 512]);
            gload16(Wl + (size_t)(n0 + r0) * Dv + k0 + c0, &lBl[w * 512]);
            gload16(Wl + (size_t)(n0 + r1) * Dv + k0 + c1, &lBl[2048 + w * 512]);
        }
        __syncthreads();
        short8 ah[4], bh[4];
#pragma unroll
        for (int mi = 0; mi < 4; mi++)
            ah[mi] = *(const short8*)&lAh[(wr*64 + mi*16 + li) * 32 + g * 8];
#pragma unroll
        for (int ni = 0; ni < 4; ni++)
            bh[ni] = *(const short8*)&lBh[(wc*64 + ni*16 + li) * 32 + g * 8];
        if (isv) {
#pragma unroll
            for (int mi = 0; mi < 4; mi++)
#pragma unroll
                for (int ni = 0; ni < 4; ni++)
                    acc[mi][ni] = mfma16(ah[mi], bh[ni], acc[mi][ni]);
        } else {
            short8 al[4], bl[4];
#pragma unroll
            for (int mi = 0; mi < 4; mi++)
                al[mi] = *(const short8*)&lAl[(wr*64 + mi*16 + li) * 32 + g * 8];
#pragma unroll
            for (int ni = 0; ni < 4; ni++)
                bl[ni] = *(const short8*)&lBl[(wc*64 + ni*16 + li) * 32 + g * 8];
#pragma unroll
            for (int mi = 0; mi < 4; mi++)
#pragma unroll
                for (int ni = 0; ni < 4; ni++) {
                    acc[mi][ni] = mfma16(ah[mi], bh[ni], acc[mi][ni]);
                    acc[mi][ni] = mfma16(ah[mi], bl[ni], acc[mi][ni]);
                    acc[mi][ni] = mfma16(al[mi], bh[ni], acc[mi][ni]);
                }
        }
    }
#pragma unroll
    for (int mi = 0; mi < 4; mi++)
#pragma unroll
        for (int ni = 0; ni < 4; ni++)
#pragma unroll
            for (int j = 0; j < 4; j++) {
                int row = m0 + wr*64 + mi*16 + g*4 + j;
                int col = n0 + wc*64 + ni*16 + li;
                float v = acc[mi][ni][j];
                short hi = f2bf(v);
                QKVh[(size_t)row * NQKV + col] = hi;
                if (!isv) QKVl[(size_t)row * NQK + col] = f2bf(v - bf2f(hi));
            }
}

// ---------------- GEMM2: out(f32) = Zb(bf16) @ W2T(bf16)^T ----------------
__global__ __launch_bounds__(256) void gemm2_kernel(const short* __restrict__ A,
                                                    const short* __restrict__ Bt,
                                                    float* __restrict__ C) {
    int m0 = blockIdx.y * 128, n0 = blockIdx.x * 128;
    __shared__ __align__(16) short lA[128 * 32];
    __shared__ __align__(16) short lB[128 * 32];
    int tid = threadIdx.x, lane = tid & 63, w = tid >> 6;
    int wr = w >> 1, wc = w & 1;
    int li = lane & 15, g = lane >> 4;
    f32x4 zero = {0.f, 0.f, 0.f, 0.f};
    f32x4 acc[4][4];
#pragma unroll
    for (int i = 0; i < 4; i++)
#pragma unroll
        for (int j = 0; j < 4; j++) acc[i][j] = zero;

    int e0 = w * 512 + lane * 8;
    int r0 = e0 >> 5, c0 = e0 & 31;
    int e1 = e0 + 2048;
    int r1 = e1 >> 5, c1 = e1 & 31;

    for (int k0 = 0; k0 < Dv; k0 += 32) {
        __syncthreads();
        gload16(A  + (size_t)(m0 + r0) * Dv + k0 + c0, &lA[w * 512]);
        gload16(A  + (size_t)(m0 + r1) * Dv + k0 + c1, &lA[2048 + w * 512]);
        gload16(Bt + (size_t)(n0 + r0) * Dv + k0 + c0, &lB[w * 512]);
        gload16(Bt + (size_t)(n0 + r1) * Dv + k0 + c1, &lB[2048 + w * 512]);
        __syncthreads();
        short8 a[4], bb[4];
#pragma unroll
        for (int mi = 0; mi < 4; mi++)
            a[mi] = *(const short8*)&lA[(wr*64 + mi*16 + li) * 32 + g * 8];
#pragma unroll
        for (int ni = 0; ni < 4; ni++)
            bb[ni] = *(const short8*)&lB[(wc*64 + ni*16 + li) * 32 + g * 8];
#pragma unroll
        for (int mi = 0; mi < 4; mi++)
#pragma unroll
            for (int ni = 0; ni < 4; ni++)
                acc[mi][ni] = mfma16(a[mi], bb[ni], acc[mi][ni]);
    }
#pragma unroll
    for (int mi = 0; mi < 4; mi++)
#pragma unroll
        for (int ni = 0; ni < 4; ni++)
#pragma unroll
            for (int j = 0; j < 4; j++) {
                int row = m0 + wr*64 + mi*16 + g*4 + j;
                int col = n0 + wc*64 + ni*16 + li;
                C[(size_t)row * Dv + col] = acc[mi][ni][j];
            }
}

// ---------------- flash attention (split-bf16 QK^T, LDS-staged K/V) ----------------
// grid (8 q-blocks of 128, 96 bh), 512 threads = 8 waves, 16 q-rows/wave.
// K hi/lo + V^T tiles staged in LDS once per block via global_load_lds with
// pre-swizzled source (chunk ^= row&7) and XOR-swizzled reads (bank-conflict-free).
__global__ __launch_bounds__(512, 6) void attn_kernel(const short* __restrict__ QKVh,
                                                      const short* __restrict__ QKVl,
                                                      const short* __restrict__ Vt,
                                                      short* __restrict__ Z) {
    int qb = blockIdx.x, bh = blockIdx.y;
    int b = bh / Hv, h = bh % Hv;
    int tid = threadIdx.x, lane = tid & 63, w = tid >> 6;   // 8 waves
    int li = lane & 15, g = lane >> 4;

    __shared__ __align__(16) short Kh[64 * 64];
    __shared__ __align__(16) short Kl[64 * 64];
    __shared__ __align__(16) short Vs[64 * 64];
    __shared__ __align__(16) short P[8][1024];
    char* Pw = (char*)&P[w][0];
    const char* Khc = (const char*)Kh;
    const char* Klc = (const char*)Kl;
    const char* Vsc = (const char*)Vs;

    int qr0 = qb * 128 + w * 16;
    const short* qhr = QKVh + (size_t)(b*Sv + qr0 + li) * NQKV + h * DKv;
    const short* qlr = QKVl + (size_t)(b*Sv + qr0 + li) * NQK  + h * DKv;
    short8 qh0 = *(const short8*)(qhr + g * 8);
    short8 qh1 = *(const short8*)(qhr + 32 + g * 8);
    short8 ql0 = *(const short8*)(qlr + g * 8);
    short8 ql1 = *(const short8*)(qlr + 32 + g * 8);

    const short* Khb = QKVh + (size_t)(b*Sv) * NQKV + Hv*DKv + h*DKv;
    const short* Klb = QKVl + (size_t)(b*Sv) * NQK  + Hv*DKv + h*DKv;
    const short* Vbase = Vt + (size_t)(bh * 64) * Sv;

    // staging: wave w covers rows w*8..w*8+7 of each 64x64 tile; lane l -> row
    // w*8+(l>>3), linear chunk l&7; source chunk pre-swizzled so reads can XOR.
    int srow = w * 8 + (lane >> 3);
    int scs  = (lane & 7) ^ (srow & 7);

    float m[4], l[4];
    f32x4 zero = {0.f, 0.f, 0.f, 0.f};
    f32x4 acc[4];
#pragma unroll
    for (int j = 0; j < 4; j++) { m[j] = -1e30f; l[j] = 0.f; }
#pragma unroll
    for (int ni = 0; ni < 4; ni++) acc[ni] = zero;

    for (int t0 = 0; t0 < Sv; t0 += 64) {
        gload16(Khb + (size_t)(t0 + srow) * NQKV + scs * 8, &Kh[w * 512]);
        gload16(Klb + (size_t)(t0 + srow) * NQK  + scs * 8, &Kl[w * 512]);
        gload16(Vbase + (size_t)srow * Sv + t0 + scs * 8,   &Vs[w * 512]);
        asm volatile("s_waitcnt vmcnt(0)" ::: "memory");
        __syncthreads();

        f32x4 s[4];
#pragma unroll
        for (int tn = 0; tn < 4; tn++) {
            int row = tn * 16 + li;
            int rb = row * 128, rs = (row & 7) << 4;
            short8 kh0 = *(const short8*)(Khc + rb + ((g << 4) ^ rs));
            short8 kh1 = *(const short8*)(Khc + rb + ((64 + (g << 4)) ^ rs));
            short8 kl0 = *(const short8*)(Klc + rb + ((g << 4) ^ rs));
            short8 kl1 = *(const short8*)(Klc + rb + ((64 + (g << 4)) ^ rs));
            f32x4 z = mfma16(qh0, kh0, zero);
            z = mfma16(qh1, kh1, z);
            z = mfma16(qh0, kl0, z);
            z = mfma16(qh1, kl1, z);
            z = mfma16(ql0, kh0, z);
            z = mfma16(ql1, kh1, z);
            s[tn] = z;
        }
#pragma unroll
        for (int tn = 0; tn < 4; tn++)
#pragma unroll
            for (int j = 0; j < 4; j++) s[tn][j] *= 0.125f;

        float p[4][4], sf[4];
#pragma unroll
        for (int j = 0; j < 4; j++) {
            float rm = fmaxf(fmaxf(s[0][j], s[1][j]), fmaxf(s[2][j], s[3][j]));
            rm = fmaxf(rm, __shfl_xor(rm, 1));
            rm = fmaxf(rm, __shfl_xor(rm, 2));
            rm = fmaxf(rm, __shfl_xor(rm, 4));
            rm = fmaxf(rm, __shfl_xor(rm, 8));
            float mn = fmaxf(m[j], rm);
            float sfj = __expf(m[j] - mn);
            float rs = 0.f;
#pragma unroll
            for (int tn = 0; tn < 4; tn++) { p[tn][j] = __expf(s[tn][j] - mn); rs += p[tn][j]; }
            rs += __shfl_xor(rs, 1);
            rs += __shfl_xor(rs, 2);
            rs += __shfl_xor(rs, 4);
            rs += __shfl_xor(rs, 8);
            l[j] = l[j] * sfj + rs;
            m[j] = mn;
            sf[j] = sfj;
        }
#pragma unroll
        for (int ni = 0; ni < 4; ni++)
#pragma unroll
            for (int j = 0; j < 4; j++) acc[ni][j] *= sf[j];

        // P -> per-wave LDS ([16 q][64 t], XOR-swizzled 16B chunks per 128B row)
#pragma unroll
        for (int tn = 0; tn < 4; tn++)
#pragma unroll
            for (int j = 0; j < 4; j++) {
                int q_l = g * 4 + j, t_l = tn * 16 + li;
                int off = (q_l * 128 + t_l * 2) ^ ((q_l & 7) << 4);
                *(short*)(Pw + off) = f2bf(p[tn][j]);
            }
        // PV from LDS
#pragma unroll
        for (int kt = 0; kt < 2; kt++) {
            int roff = (li * 128 + kt * 64 + g * 16) ^ ((li & 7) << 4);
            short8 ap = *(const short8*)(Pw + roff);
#pragma unroll
            for (int ni = 0; ni < 4; ni++) {
                int dk = ni * 16 + li;
                int vb = dk * 128 + ((((kt * 4 + g) << 4)) ^ ((dk & 7) << 4));
                short8 bv = *(const short8*)(Vsc + vb);
                acc[ni] = mfma16(ap, bv, acc[ni]);
            }
        }
        __syncthreads();   // all waves done reading K/V tiles before restage
    }
    float inv[4];
#pragma unroll
    for (int j = 0; j < 4; j++) inv[j] = 1.f / l[j];
#pragma unroll
    for (int ni = 0; ni < 4; ni++)
#pragma unroll
        for (int j = 0; j < 4; j++) {
            int row = b*Sv + qr0 + g*4 + j;
            int col = h*DKv + ni*16 + li;
            Z[(size_t)row * Dv + col] = f2bf(acc[ni][j] * inv[j]);
        }
}

extern "C" void kernel_launch(void* const* d_in, const int* in_sizes, int n_in,
                              void* d_out, int out_size, void* d_ws, size_t ws_size,
                              hipStream_t stream) {
    const float* x  = (const float*)d_in[0];
    const float* Wq = (const float*)d_in[1];
    const float* Wk = (const float*)d_in[2];
    const float* Wv = (const float*)d_in[3];
    const float* W  = (const float*)d_in[4];
    float* out = (float*)d_out;

    short* xh   = (short*)d_ws;                        // 8192*768
    short* xl   = xh   + (size_t)Mv * Dv;              // 8192*768
    short* Wh   = xl   + (size_t)Mv * Dv;              // 2304*768
    short* Wl   = Wh   + (size_t)NQKV * Dv;            // 2304*768
    short* W2T  = Wl   + (size_t)NQKV * Dv;            // 768*768
    short* QKVh = W2T  + (size_t)Dv * Dv;              // 8192*2304
    short* QKVl = QKVh + (size_t)Mv * NQKV;            // 8192*1536
    short* Vt   = QKVl + (size_t)Mv * NQK;             // 96*64*1024
    short* Zb   = Vt   + (size_t)Bv*Hv*DKv * Sv;       // 8192*768

    split_x_kernel<<<dim3(Mv * Dv / (256 * 8)), 256, 0, stream>>>(x, xh, xl);
    pack_wqkv_kernel<<<dim3(Dv/64, Hv, 3), 256, 0, stream>>>(Wq, Wk, Wv, Wh, Wl);
    transpose_cast_kernel<<<dim3(Dv/64, Dv/64), 256, 0, stream>>>(W, Dv, W2T, Dv);
    gemm1_kernel<<<dim3(NQKV/128, Mv/128), 256, 0, stream>>>(xh, xl, Wh, Wl, QKVh, QKVl);
    vtrans_kernel<<<dim3(Sv/64, Bv*Hv), 256, 0, stream>>>(QKVh, Vt);
    attn_kernel<<<dim3(Sv/128, Bv*Hv), 512, 0, stream>>>(QKVh, QKVl, Vt, Zb);
    gemm2_kernel<<<dim3(Dv/128, Mv/128), 256, 0, stream>>>(Zb, W2T, out);
}

// Round 4
// 301.198 us; speedup vs baseline: 1.3928x; 1.2444x over previous
//
#include <hip/hip_runtime.h>

#define Bv 8
#define Sv 1024
#define Dv 768
#define Hv 12
#define DKv 64
#define Mv (Bv*Sv)          // 8192
#define NQKV (3*Hv*DKv)     // 2304
#define NQK (2*Hv*DKv)      // 1536

typedef __attribute__((ext_vector_type(8))) short short8;
typedef __attribute__((ext_vector_type(4))) float f32x4;

__device__ __forceinline__ short f2bf(float f) {
    unsigned u = __builtin_bit_cast(unsigned, f);
    u += 0x7fffu + ((u >> 16) & 1u);
    return (short)(u >> 16);
}
__device__ __forceinline__ float bf2f(short h) {
    return __builtin_bit_cast(float, (unsigned)(unsigned short)h << 16);
}

__device__ __forceinline__ f32x4 mfma16(short8 a, short8 b, f32x4 c) {
    return __builtin_amdgcn_mfma_f32_16x16x32_bf16(a, b, c, 0, 0, 0);
}

__device__ __forceinline__ void gload16(const short* g, const short* l) {
    __builtin_amdgcn_global_load_lds(
        (const __attribute__((address_space(1))) unsigned int*)g,
        (__attribute__((address_space(3))) unsigned int*)(short*)l, 16, 0, 0);
}

// ---------------- split x (f32 -> bf16 hi + bf16 lo), 8 elems/thread ----------------
__global__ void split_x_kernel(const float* __restrict__ x, short* __restrict__ xh,
                               short* __restrict__ xl) {
    int t = blockIdx.x * 256 + threadIdx.x;
    const float4* f = (const float4*)x + (size_t)t * 2;
    float4 a = f[0], b = f[1];
    float v[8] = {a.x,a.y,a.z,a.w,b.x,b.y,b.z,b.w};
    short8 oh, ol;
#pragma unroll
    for (int k = 0; k < 8; k++) {
        short hi = f2bf(v[k]);
        oh[k] = hi;
        ol[k] = f2bf(v[k] - bf2f(hi));
    }
    *((short8*)xh + t) = oh;
    *((short8*)xl + t) = ol;
}

// ---------------- pack Wq/Wk/Wv -> WqkvT[n][d] hi/lo ----------------
__global__ void pack_wqkv_kernel(const float* __restrict__ Wq, const float* __restrict__ Wk,
                                 const float* __restrict__ Wv, short* __restrict__ Wh,
                                 short* __restrict__ Wl) {
    int dt = blockIdx.x;
    int h  = blockIdx.y;
    int p  = blockIdx.z;
    const float* S = (p == 0 ? Wq : (p == 1 ? Wk : Wv)) + (size_t)h * Dv * DKv;
    __shared__ float lds[64][65];
    int t = threadIdx.x;
    int d0 = dt * 64;
#pragma unroll
    for (int i = 0; i < 4; i++) {
        int v = t + i * 256;
        int r = v >> 4, c4 = v & 15;
        float4 f = *(const float4*)&S[(size_t)(d0 + r) * DKv + c4 * 4];
        lds[r][c4*4+0] = f.x; lds[r][c4*4+1] = f.y; lds[r][c4*4+2] = f.z; lds[r][c4*4+3] = f.w;
    }
    __syncthreads();
#pragma unroll
    for (int i = 0; i < 2; i++) {
        int v = t + i * 256;
        int kk = v >> 3, dl0 = (v & 7) * 8;
        short8 oh, ol;
#pragma unroll
        for (int k = 0; k < 8; k++) {
            float f = lds[dl0 + k][kk];
            short hi = f2bf(f);
            oh[k] = hi;
            ol[k] = f2bf(f - bf2f(hi));
        }
        size_t base = (size_t)(p*768 + h*64 + kk) * Dv + d0 + dl0;
        *(short8*)&Wh[base] = oh;
        if (p < 2) *(short8*)&Wl[base] = ol;   // V never feeds scores
    }
}

// ---------------- transpose+cast (single bf16): D[c][r] = S[r][c] ----------------
__global__ void transpose_cast_kernel(const float* __restrict__ S, int S_cols,
                                      short* __restrict__ D, int D_ld) {
    int c0 = blockIdx.x * 64, r0 = blockIdx.y * 64;
    __shared__ float lds[64][65];
    int t = threadIdx.x;
#pragma unroll
    for (int i = 0; i < 4; i++) {
        int v = t + i * 256;
        int r = v >> 4, c4 = v & 15;
        float4 f = *(const float4*)&S[(size_t)(r0 + r) * S_cols + c0 + c4 * 4];
        lds[r][c4*4+0] = f.x; lds[r][c4*4+1] = f.y; lds[r][c4*4+2] = f.z; lds[r][c4*4+3] = f.w;
    }
    __syncthreads();
#pragma unroll
    for (int i = 0; i < 2; i++) {
        int v = t + i * 256;
        int oc = v >> 3, rl0 = (v & 7) * 8;
        short8 o;
#pragma unroll
        for (int k = 0; k < 8; k++) o[k] = f2bf(lds[rl0 + k][oc]);
        *(short8*)&D[(size_t)(c0 + oc) * D_ld + r0 + rl0] = o;
    }
}

// ---------------- V transpose: Vt[bh*64+dk][s] = Vhi[s][dk] ----------------
__global__ void vtrans_kernel(const short* __restrict__ QKVh, short* __restrict__ Vt) {
    int sc = blockIdx.x;
    int bh = blockIdx.y;
    int b = bh / Hv, h = bh % Hv;
    __shared__ __align__(16) short lds[64][72];
    int t = threadIdx.x;
    int s0 = sc * 64;
#pragma unroll
    for (int i = 0; i < 2; i++) {
        int v = t + i * 256;
        int sl = v >> 3, c0 = (v & 7) * 8;
        short8 xv = *(const short8*)&QKVh[(size_t)(b*Sv + s0 + sl) * NQKV + NQK + h*DKv + c0];
        *(short8*)&lds[sl][c0] = xv;
    }
    __syncthreads();
#pragma unroll
    for (int i = 0; i < 2; i++) {
        int v = t + i * 256;
        int dk = v >> 3, tl0 = (v & 7) * 8;
        short8 o;
#pragma unroll
        for (int k = 0; k < 8; k++) o[k] = lds[tl0 + k][dk];
        *(short8*)&Vt[(size_t)(bh*64 + dk) * Sv + s0 + tl0] = o;
    }
}

// XCD-affinity block swizzle for 1D grids over (x:NX, y:64): blocks sharing y
// (A-panel) land on the same XCD (id % 8 heuristic).
__device__ __forceinline__ void swz_xy(int n, int& xbl, int& ybl) {
    int cx = n & 7, k = n >> 3;
    ybl = cx + 8 * (k & 7);
    xbl = k >> 3;
}

// ---------------- GEMM1 (split): QKV = (xh+xl) @ (Wh+Wl)^T ----------------
__global__ __launch_bounds__(256) void gemm1_kernel(const short* __restrict__ xh,
                                                    const short* __restrict__ xl,
                                                    const short* __restrict__ Wh,
                                                    const short* __restrict__ Wl,
                                                    short* __restrict__ QKVh,
                                                    short* __restrict__ QKVl) {
    int xbl, ybl;
    swz_xy(blockIdx.x, xbl, ybl);
    int m0 = ybl * 128, n0 = xbl * 128;
    bool isv = (n0 >= NQK);
    __shared__ __align__(16) short lAh[128 * 32];
    __shared__ __align__(16) short lAl[128 * 32];
    __shared__ __align__(16) short lBh[128 * 32];
    __shared__ __align__(16) short lBl[128 * 32];
    int tid = threadIdx.x, lane = tid & 63, w = tid >> 6;
    int wr = w >> 1, wc = w & 1;
    int li = lane & 15, g = lane >> 4;
    f32x4 zero = {0.f, 0.f, 0.f, 0.f};
    f32x4 acc[4][4];
#pragma unroll
    for (int i = 0; i < 4; i++)
#pragma unroll
        for (int j = 0; j < 4; j++) acc[i][j] = zero;

    int e0 = w * 512 + lane * 8;
    int r0 = e0 >> 5, c0 = e0 & 31;
    int e1 = e0 + 2048;
    int r1 = e1 >> 5, c1 = e1 & 31;

    for (int k0 = 0; k0 < Dv; k0 += 32) {
        __syncthreads();
        gload16(xh + (size_t)(m0 + r0) * Dv + k0 + c0, &lAh[w * 512]);
        gload16(xh + (size_t)(m0 + r1) * Dv + k0 + c1, &lAh[2048 + w * 512]);
        gload16(Wh + (size_t)(n0 + r0) * Dv + k0 + c0, &lBh[w * 512]);
        gload16(Wh + (size_t)(n0 + r1) * Dv + k0 + c1, &lBh[2048 + w * 512]);
        if (!isv) {
            gload16(xl + (size_t)(m0 + r0) * Dv + k0 + c0, &lAl[w * 512]);
            gload16(xl + (size_t)(m0 + r1) * Dv + k0 + c1, &lAl[2048 + w * 512]);
            gload16(Wl + (size_t)(n0 + r0) * Dv + k0 + c0, &lBl[w * 512]);
            gload16(Wl + (size_t)(n0 + r1) * Dv + k0 + c1, &lBl[2048 + w * 512]);
        }
        __syncthreads();
        short8 ah[4], bh[4];
#pragma unroll
        for (int mi = 0; mi < 4; mi++)
            ah[mi] = *(const short8*)&lAh[(wr*64 + mi*16 + li) * 32 + g * 8];
#pragma unroll
        for (int ni = 0; ni < 4; ni++)
            bh[ni] = *(const short8*)&lBh[(wc*64 + ni*16 + li) * 32 + g * 8];
        if (isv) {
#pragma unroll
            for (int mi = 0; mi < 4; mi++)
#pragma unroll
                for (int ni = 0; ni < 4; ni++)
                    acc[mi][ni] = mfma16(ah[mi], bh[ni], acc[mi][ni]);
        } else {
            short8 al[4], bl[4];
#pragma unroll
            for (int mi = 0; mi < 4; mi++)
                al[mi] = *(const short8*)&lAl[(wr*64 + mi*16 + li) * 32 + g * 8];
#pragma unroll
            for (int ni = 0; ni < 4; ni++)
                bl[ni] = *(const short8*)&lBl[(wc*64 + ni*16 + li) * 32 + g * 8];
#pragma unroll
            for (int mi = 0; mi < 4; mi++)
#pragma unroll
                for (int ni = 0; ni < 4; ni++) {
                    acc[mi][ni] = mfma16(ah[mi], bh[ni], acc[mi][ni]);
                    acc[mi][ni] = mfma16(ah[mi], bl[ni], acc[mi][ni]);
                    acc[mi][ni] = mfma16(al[mi], bh[ni], acc[mi][ni]);
                }
        }
    }
#pragma unroll
    for (int mi = 0; mi < 4; mi++)
#pragma unroll
        for (int ni = 0; ni < 4; ni++)
#pragma unroll
            for (int j = 0; j < 4; j++) {
                int row = m0 + wr*64 + mi*16 + g*4 + j;
                int col = n0 + wc*64 + ni*16 + li;
                float v = acc[mi][ni][j];
                short hi = f2bf(v);
                QKVh[(size_t)row * NQKV + col] = hi;
                if (!isv) QKVl[(size_t)row * NQK + col] = f2bf(v - bf2f(hi));
            }
}

// ---------------- GEMM2: out(f32) = Zb(bf16) @ W2T(bf16)^T ----------------
__global__ __launch_bounds__(256) void gemm2_kernel(const short* __restrict__ A,
                                                    const short* __restrict__ Bt,
                                                    float* __restrict__ C) {
    int xbl, ybl;
    swz_xy(blockIdx.x, xbl, ybl);
    int m0 = ybl * 128, n0 = xbl * 128;
    __shared__ __align__(16) short lA[128 * 32];
    __shared__ __align__(16) short lB[128 * 32];
    int tid = threadIdx.x, lane = tid & 63, w = tid >> 6;
    int wr = w >> 1, wc = w & 1;
    int li = lane & 15, g = lane >> 4;
    f32x4 zero = {0.f, 0.f, 0.f, 0.f};
    f32x4 acc[4][4];
#pragma unroll
    for (int i = 0; i < 4; i++)
#pragma unroll
        for (int j = 0; j < 4; j++) acc[i][j] = zero;

    int e0 = w * 512 + lane * 8;
    int r0 = e0 >> 5, c0 = e0 & 31;
    int e1 = e0 + 2048;
    int r1 = e1 >> 5, c1 = e1 & 31;

    for (int k0 = 0; k0 < Dv; k0 += 32) {
        __syncthreads();
        gload16(A  + (size_t)(m0 + r0) * Dv + k0 + c0, &lA[w * 512]);
        gload16(A  + (size_t)(m0 + r1) * Dv + k0 + c1, &lA[2048 + w * 512]);
        gload16(Bt + (size_t)(n0 + r0) * Dv + k0 + c0, &lB[w * 512]);
        gload16(Bt + (size_t)(n0 + r1) * Dv + k0 + c1, &lB[2048 + w * 512]);
        __syncthreads();
        short8 a[4], bb[4];
#pragma unroll
        for (int mi = 0; mi < 4; mi++)
            a[mi] = *(const short8*)&lA[(wr*64 + mi*16 + li) * 32 + g * 8];
#pragma unroll
        for (int ni = 0; ni < 4; ni++)
            bb[ni] = *(const short8*)&lB[(wc*64 + ni*16 + li) * 32 + g * 8];
#pragma unroll
        for (int mi = 0; mi < 4; mi++)
#pragma unroll
            for (int ni = 0; ni < 4; ni++)
                acc[mi][ni] = mfma16(a[mi], bb[ni], acc[mi][ni]);
    }
#pragma unroll
    for (int mi = 0; mi < 4; mi++)
#pragma unroll
        for (int ni = 0; ni < 4; ni++)
#pragma unroll
            for (int j = 0; j < 4; j++) {
                int row = m0 + wr*64 + mi*16 + g*4 + j;
                int col = n0 + wc*64 + ni*16 + li;
                C[(size_t)row * Dv + col] = acc[mi][ni][j];
            }
}

// ---------------- flash attention ----------------
// 384 blocks (XCD-affine: 4 blocks per head on one XCD), 512 threads = 8 waves,
// 32 q-rows/wave as 2x16 chunks. K hi/lo + V^T double-buffered in LDS via
// global_load_lds (pre-swizzled source, XOR-swizzled reads), counted vmcnt.
__global__ __launch_bounds__(512, 4) void attn_kernel(const short* __restrict__ QKVh,
                                                      const short* __restrict__ QKVl,
                                                      const short* __restrict__ Vt,
                                                      short* __restrict__ Z) {
    int n = blockIdx.x;
    int cx = n & 7, kb = n >> 3;
    int bh = cx + 8 * (kb % 12);
    int qb = kb / 12;                 // 0..3, 256 q-rows each
    int b = bh / Hv, h = bh % Hv;
    int tid = threadIdx.x, lane = tid & 63, w = tid >> 6;
    int li = lane & 15, g = lane >> 4;

    __shared__ __align__(16) short Kh[2][64 * 64];
    __shared__ __align__(16) short Kl[2][64 * 64];
    __shared__ __align__(16) short Vs[2][64 * 64];
    __shared__ __align__(16) short P[8][1024];
    char* Pw = (char*)&P[w][0];

    int qr0 = qb * 256 + w * 32;
    short8 qh[2][2], ql[2][2];
#pragma unroll
    for (int u = 0; u < 2; u++) {
        const short* qhr = QKVh + (size_t)(b*Sv + qr0 + u*16 + li) * NQKV + h * DKv;
        const short* qlr = QKVl + (size_t)(b*Sv + qr0 + u*16 + li) * NQK  + h * DKv;
        qh[u][0] = *(const short8*)(qhr + g * 8);
        qh[u][1] = *(const short8*)(qhr + 32 + g * 8);
        ql[u][0] = *(const short8*)(qlr + g * 8);
        ql[u][1] = *(const short8*)(qlr + 32 + g * 8);
    }

    const short* Khb = QKVh + (size_t)(b*Sv) * NQKV + Hv*DKv + h*DKv;
    const short* Klb = QKVl + (size_t)(b*Sv) * NQK  + Hv*DKv + h*DKv;
    const short* Vbase = Vt + (size_t)(bh * 64) * Sv;

    int srow = w * 8 + (lane >> 3);
    int scs  = (lane & 7) ^ (srow & 7);

    float m[2][4], l[2][4], sf[2][4];
    f32x4 zero = {0.f, 0.f, 0.f, 0.f};
    f32x4 acc[2][4];
#pragma unroll
    for (int u = 0; u < 2; u++)
#pragma unroll
        for (int j = 0; j < 4; j++) { m[u][j] = -1e30f; l[u][j] = 0.f; }
#pragma unroll
    for (int u = 0; u < 2; u++)
#pragma unroll
        for (int ni = 0; ni < 4; ni++) acc[u][ni] = zero;

    // prologue: stage tile 0 into buffer 0
    gload16(Khb + (size_t)srow * NQKV + scs * 8, &Kh[0][w * 512]);
    gload16(Klb + (size_t)srow * NQK  + scs * 8, &Kl[0][w * 512]);
    gload16(Vbase + (size_t)srow * Sv + scs * 8, &Vs[0][w * 512]);

    for (int t = 0; t < 16; t++) {
        int cur = t & 1;
        if (t < 15) {
            int t0 = (t + 1) * 64;
            gload16(Khb + (size_t)(t0 + srow) * NQKV + scs * 8, &Kh[cur ^ 1][w * 512]);
            gload16(Klb + (size_t)(t0 + srow) * NQK  + scs * 8, &Kl[cur ^ 1][w * 512]);
            gload16(Vbase + (size_t)srow * Sv + t0 + scs * 8,   &Vs[cur ^ 1][w * 512]);
            asm volatile("s_waitcnt vmcnt(3)" ::: "memory");
        } else {
            asm volatile("s_waitcnt vmcnt(0)" ::: "memory");
        }
        __syncthreads();
        const char* Khc = (const char*)Kh[cur];
        const char* Klc = (const char*)Kl[cur];
        const char* Vsc = (const char*)Vs[cur];

#pragma unroll
        for (int u = 0; u < 2; u++) {
            f32x4 s[4];
#pragma unroll
            for (int tn = 0; tn < 4; tn++) {
                int row = tn * 16 + li;
                int rb = row * 128, rs = (row & 7) << 4;
                short8 kh0 = *(const short8*)(Khc + rb + ((g << 4) ^ rs));
                short8 kh1 = *(const short8*)(Khc + rb + ((64 + (g << 4)) ^ rs));
                short8 kl0 = *(const short8*)(Klc + rb + ((g << 4) ^ rs));
                short8 kl1 = *(const short8*)(Klc + rb + ((64 + (g << 4)) ^ rs));
                f32x4 z = mfma16(qh[u][0], kh0, zero);
                z = mfma16(qh[u][1], kh1, z);
                z = mfma16(qh[u][0], kl0, z);
                z = mfma16(qh[u][1], kl1, z);
                z = mfma16(ql[u][0], kh0, z);
                z = mfma16(ql[u][1], kh1, z);
                s[tn] = z;
            }
#pragma unroll
            for (int tn = 0; tn < 4; tn++)
#pragma unroll
                for (int j = 0; j < 4; j++) s[tn][j] *= 0.125f;

            float p[4][4];
#pragma unroll
            for (int j = 0; j < 4; j++) {
                float rm = fmaxf(fmaxf(s[0][j], s[1][j]), fmaxf(s[2][j], s[3][j]));
                rm = fmaxf(rm, __shfl_xor(rm, 1));
                rm = fmaxf(rm, __shfl_xor(rm, 2));
                rm = fmaxf(rm, __shfl_xor(rm, 4));
                rm = fmaxf(rm, __shfl_xor(rm, 8));
                float mn = fmaxf(m[u][j], rm);
                float sfj = __expf(m[u][j] - mn);
                float rs = 0.f;
#pragma unroll
                for (int tn = 0; tn < 4; tn++) { p[tn][j] = __expf(s[tn][j] - mn); rs += p[tn][j]; }
                rs += __shfl_xor(rs, 1);
                rs += __shfl_xor(rs, 2);
                rs += __shfl_xor(rs, 4);
                rs += __shfl_xor(rs, 8);
                l[u][j] = l[u][j] * sfj + rs;
                m[u][j] = mn;
                sf[u][j] = sfj;
            }
#pragma unroll
            for (int ni = 0; ni < 4; ni++)
#pragma unroll
                for (int j = 0; j < 4; j++) acc[u][ni][j] *= sf[u][j];

#pragma unroll
            for (int tn = 0; tn < 4; tn++)
#pragma unroll
                for (int j = 0; j < 4; j++) {
                    int q_l = g * 4 + j, t_l = tn * 16 + li;
                    int off = (q_l * 128 + t_l * 2) ^ ((q_l & 7) << 4);
                    *(short*)(Pw + off) = f2bf(p[tn][j]);
                }
#pragma unroll
            for (int kt = 0; kt < 2; kt++) {
                int roff = (li * 128 + kt * 64 + g * 16) ^ ((li & 7) << 4);
                short8 ap = *(const short8*)(Pw + roff);
#pragma unroll
                for (int ni = 0; ni < 4; ni++) {
                    int dk = ni * 16 + li;
                    int vb = dk * 128 + ((((kt * 4 + g) << 4)) ^ ((dk & 7) << 4));
                    short8 bv = *(const short8*)(Vsc + vb);
                    acc[u][ni] = mfma16(ap, bv, acc[u][ni]);
                }
            }
        }
        __syncthreads();   // all waves done with buf[cur] before next restage
    }
#pragma unroll
    for (int u = 0; u < 2; u++) {
        float inv[4];
#pragma unroll
        for (int j = 0; j < 4; j++) inv[j] = 1.f / l[u][j];
#pragma unroll
        for (int ni = 0; ni < 4; ni++)
#pragma unroll
            for (int j = 0; j < 4; j++) {
                int row = b*Sv + qr0 + u*16 + g*4 + j;
                int col = h*DKv + ni*16 + li;
                Z[(size_t)row * Dv + col] = f2bf(acc[u][ni][j] * inv[j]);
            }
    }
}

extern "C" void kernel_launch(void* const* d_in, const int* in_sizes, int n_in,
                              void* d_out, int out_size, void* d_ws, size_t ws_size,
                              hipStream_t stream) {
    const float* x  = (const float*)d_in[0];
    const float* Wq = (const float*)d_in[1];
    const float* Wk = (const float*)d_in[2];
    const float* Wv = (const float*)d_in[3];
    const float* W  = (const float*)d_in[4];
    float* out = (float*)d_out;

    short* xh   = (short*)d_ws;                        // 8192*768
    short* xl   = xh   + (size_t)Mv * Dv;
    short* Wh   = xl   + (size_t)Mv * Dv;
    short* Wl   = Wh   + (size_t)NQKV * Dv;
    short* W2T  = Wl   + (size_t)NQKV * Dv;
    short* QKVh = W2T  + (size_t)Dv * Dv;
    short* QKVl = QKVh + (size_t)Mv * NQKV;
    short* Vt   = QKVl + (size_t)Mv * NQK;
    short* Zb   = Vt   + (size_t)Bv*Hv*DKv * Sv;

    split_x_kernel<<<dim3(Mv * Dv / (256 * 8)), 256, 0, stream>>>(x, xh, xl);
    pack_wqkv_kernel<<<dim3(Dv/64, Hv, 3), 256, 0, stream>>>(Wq, Wk, Wv, Wh, Wl);
    transpose_cast_kernel<<<dim3(Dv/64, Dv/64), 256, 0, stream>>>(W, Dv, W2T, Dv);
    gemm1_kernel<<<dim3((NQKV/128) * (Mv/128)), 256, 0, stream>>>(xh, xl, Wh, Wl, QKVh, QKVl);
    vtrans_kernel<<<dim3(Sv/64, Bv*Hv), 256, 0, stream>>>(QKVh, Vt);
    attn_kernel<<<dim3(384), 512, 0, stream>>>(QKVh, QKVl, Vt, Zb);
    gemm2_kernel<<<dim3((Dv/128) * (Mv/128)), 256, 0, stream>>>(Zb, W2T, out);
}